// Round 4
// baseline (341.557 us; speedup 1.0000x reference)
//
#include <hip/hip_runtime.h>

// AdaptiveSpectrumLayer: B=128, H=T=512, F=16, HID=64, NF=257
// v3: k_gemm restructured (N-split 160, 512 blocks = 2/CU, prefetch issued after
// barrier-2 so it overlaps MFMA; 1x A-recompute per N-half). k_csd rewritten
// conflict-free via autocorr symmetry (lags 0..256, mirrored DFT).

#define NF_ 257
#define KDIM 16448   // NF_*64
#define NPAD 320
#define SPK 8

typedef __attribute__((ext_vector_type(8))) short short8;
typedef __attribute__((ext_vector_type(4))) float floatx4;

__device__ __forceinline__ unsigned int f2bf(float x) {
  union { float f; unsigned int u; } v; v.f = x;
  return (v.u + 0x7FFFu + ((v.u >> 16) & 1u)) >> 16;
}
__device__ __forceinline__ float bf2f(unsigned short u) {
  union { unsigned int u; float f; } v; v.u = ((unsigned int)u) << 16;
  return v.f;
}

// ---------- K0: W_gate (16448 x 257 f32) -> wgt bf16, transposed+padded (320 x 16448)
__global__ __launch_bounds__(256) void k_wgt(const float* __restrict__ Wg,
                                             unsigned short* __restrict__ wgt) {
  __shared__ float tile[32][33];
  const int tid = threadIdx.x;
  const int k0 = blockIdx.x * 32, n0 = blockIdx.y * 32;
  const int c = tid & 31, r = tid >> 5;
#pragma unroll
  for (int j = 0; j < 4; ++j) {
    int rr = r + j * 8;
    int n = n0 + c;
    tile[rr][c] = (n < NF_) ? Wg[(k0 + rr) * NF_ + n] : 0.f;
  }
  __syncthreads();
#pragma unroll
  for (int j = 0; j < 4; ++j) {
    int nn = r + j * 8;
    wgt[(n0 + nn) * KDIM + k0 + c] = (unsigned short)f2bf(tile[c][nn]);
  }
}

// ---------- K1: csd[b][k] = (1/(256*sqrt(512))) * DFT_t( autocorr(s)[t-255] )
// One block per batch. Autocorr via symmetry: lags 0..256 only, conflict-free
// (sl[tau] uniform broadcast, sl[tau+l] stride-1), zero-padded. Mirrored DFT.
__global__ __launch_bounds__(256) void k_csd(const float* __restrict__ x,
                                             float* __restrict__ csd) {
  __shared__ float sl[768];   // [0,512) data, [512,768) zeros
  __shared__ float ac[257];
  __shared__ float red[4];
  const int tid = threadIdx.x, bb = blockIdx.x;
  for (int t = tid; t < 768; t += 256) {
    float v = 0.f;
    if (t < 512) {
      const float4* xp = (const float4*)(x + (bb * 512 + t) * 16);
      float4 a = xp[0], c = xp[1], d = xp[2], e = xp[3];
      v = a.x + a.y + a.z + a.w + c.x + c.y + c.z + c.w +
          d.x + d.y + d.z + d.w + e.x + e.y + e.z + e.w;
    }
    sl[t] = v;
  }
  __syncthreads();
  // lag = tid (0..255): uniform-broadcast float4 + stride-1 lane reads
  {
    float a0 = 0.f, a1 = 0.f, a2 = 0.f, a3 = 0.f;
    for (int tau = 0; tau < 512; tau += 4) {
      float4 u = *(const float4*)&sl[tau];     // wave-uniform broadcast
      float v0 = sl[tau + tid];                // stride-1 across lanes
      float v1 = sl[tau + tid + 1];
      float v2 = sl[tau + tid + 2];
      float v3 = sl[tau + tid + 3];
      a0 = fmaf(u.x, v0, a0);
      a1 = fmaf(u.y, v1, a1);
      a2 = fmaf(u.z, v2, a2);
      a3 = fmaf(u.w, v3, a3);
    }
    ac[tid] = (a0 + a1) + (a2 + a3);
  }
  // lag 256 via block reduce
  {
    float p = sl[tid] * sl[tid + 256];
#pragma unroll
    for (int off = 32; off; off >>= 1) p += __shfl_down(p, off);
    if ((tid & 63) == 0) red[tid >> 6] = p;
  }
  __syncthreads();
  if (tid == 0) ac[256] = red[0] + red[1] + red[2] + red[3];
  __syncthreads();
  // DFT over t of ol[t] = ac[|t-255|]; thread = bin k = tid; bin 256 redundant.
  const float S1 = 0.04419417382f / 256.f;
  float sth, cth;
  __sincosf((float)tid * 0.01227184630f, &sth, &cth);  // 2*pi/512
  float c = 1.f, s = 0.f, re = 0.f, im = 0.f, re256 = 0.f, sgn = 1.f;
  for (int t = 0; t < 512; ++t) {
    int d = t - 255;
    float ov = ac[d < 0 ? -d : d];             // uniform broadcast
    re = fmaf(ov, c, re);
    im = fmaf(-ov, s, im);
    re256 = fmaf(sgn, ov, re256);
    sgn = -sgn;
    float nc = fmaf(c, cth, -s * sth);
    s = fmaf(s, cth, c * sth);
    c = nc;
  }
  *(float2*)(csd + (bb * NF_ + tid) * 2) = make_float2(re * S1, im * S1);
  if (tid == 0)
    *(float2*)(csd + (bb * NF_ + 256) * 2) = make_float2(re256 * S1, 0.f);
}

// ---------- K2: fftc[b][k][f] = ortho-rfft(x)[k,f] + csd[b][k]
// grid (4,128): fq = f-quartet, bb = batch. thread = one k-bin, 4 f accumulators.
__global__ __launch_bounds__(256) void k_fft(const float* __restrict__ x,
                                             const float* __restrict__ csd,
                                             float* __restrict__ fftc) {
  __shared__ float xs[512 * 4];
  __shared__ float red[4][4];
  const int tid = threadIdx.x, fq = blockIdx.x, bb = blockIdx.y;
  for (int t = tid; t < 512; t += 256)
    *(float4*)&xs[t * 4] = *(const float4*)(x + (bb * 512 + t) * 16 + fq * 4);
  __syncthreads();
  const int k = tid;
  float sth, cth;
  __sincosf((float)k * 0.01227184630f, &sth, &cth);
  float c = 1.f, s = 0.f;
  float re0 = 0.f, re1 = 0.f, re2 = 0.f, re3 = 0.f;
  float im0 = 0.f, im1 = 0.f, im2 = 0.f, im3 = 0.f;
  for (int t = 0; t < 512; ++t) {
    float4 xv = *(const float4*)&xs[t * 4];   // broadcast (all lanes same addr)
    re0 = fmaf(xv.x, c, re0); im0 = fmaf(-xv.x, s, im0);
    re1 = fmaf(xv.y, c, re1); im1 = fmaf(-xv.y, s, im1);
    re2 = fmaf(xv.z, c, re2); im2 = fmaf(-xv.z, s, im2);
    re3 = fmaf(xv.w, c, re3); im3 = fmaf(-xv.w, s, im3);
    float nc = fmaf(c, cth, -s * sth);
    s = fmaf(s, cth, c * sth);
    c = nc;
  }
  const float S = 0.04419417382f;  // 1/sqrt(512)
  float2 cz = *(const float2*)(csd + (bb * NF_ + k) * 2);
  float* o = fftc + ((bb * NF_ + k) * 16 + fq * 4) * 2;
  o[0] = re0 * S + cz.x; o[1] = im0 * S + cz.y;
  o[2] = re1 * S + cz.x; o[3] = im1 * S + cz.y;
  o[4] = re2 * S + cz.x; o[5] = im2 * S + cz.y;
  o[6] = re3 * S + cz.x; o[7] = im3 * S + cz.y;
  // k = 256: re = sum_t (-1)^t x[t]; im = 0. Pair-diff + wave/block reduce.
  const int t0 = tid * 2;
  float p0 = xs[t0 * 4 + 0] - xs[t0 * 4 + 4];
  float p1 = xs[t0 * 4 + 1] - xs[t0 * 4 + 5];
  float p2 = xs[t0 * 4 + 2] - xs[t0 * 4 + 6];
  float p3 = xs[t0 * 4 + 3] - xs[t0 * 4 + 7];
#pragma unroll
  for (int off = 32; off; off >>= 1) {
    p0 += __shfl_down(p0, off);
    p1 += __shfl_down(p1, off);
    p2 += __shfl_down(p2, off);
    p3 += __shfl_down(p3, off);
  }
  if ((tid & 63) == 0) {
    red[tid >> 6][0] = p0; red[tid >> 6][1] = p1;
    red[tid >> 6][2] = p2; red[tid >> 6][3] = p3;
  }
  __syncthreads();
  if (tid == 0) {
    float2 cz2 = *(const float2*)(csd + (bb * NF_ + 256) * 2);
#pragma unroll
    for (int j = 0; j < 4; ++j) {
      float r = red[0][j] + red[1][j] + red[2][j] + red[3][j];
      float* oo = fftc + ((bb * NF_ + 256) * 16 + fq * 4 + j) * 2;
      oo[0] = r * S + cz2.x;
      oo[1] = cz2.y;
    }
  }
}

// ---------- K3: new_fft[b][n][f] from recomputed proj + per-freq complexifier
__global__ __launch_bounds__(256) void k_new(const float* __restrict__ fftc,
                                             const float* __restrict__ W_proj,
                                             const float* __restrict__ b_proj,
                                             const float* __restrict__ mag_w,
                                             const float* __restrict__ mag_b,
                                             const float* __restrict__ phase_w,
                                             const float* __restrict__ phase_b,
                                             float* __restrict__ nf) {
  __shared__ float wp[256], bp[64];
  const int tid = threadIdx.x;
  wp[tid] = W_proj[tid];
  if (tid < 64) bp[tid] = b_proj[tid];
  __syncthreads();
  const int idx = blockIdx.x * 256 + tid;  // < 128*257*16
  const int bn = idx >> 4;
  const int n = bn % NF_;
  float2 z = *(const float2*)(fftc + idx * 2);
  float d = z.x * z.x + z.y * z.y;
  float ir = d > 0.f ? rsqrtf(d) : 0.f;
  float mag = d * ir;
  float sn = z.y * ir;
  float cs = d > 0.f ? z.x * ir : 1.f;
  float fr = (float)n * 0.1953125f;  // 100/512
  float am = 0.f, ap = 0.f;
#pragma unroll 8
  for (int h = 0; h < 64; ++h) {
    float p = fmaf(mag, wp[h], fmaf(sn, wp[64 + h], fmaf(cs, wp[128 + h],
              fmaf(fr, wp[192 + h], bp[h]))));
    p = fmaxf(p, 0.f);
    am = fmaf(p, mag_w[n * 64 + h], am);
    ap = fmaf(p, phase_w[n * 64 + h], ap);
  }
  float m = fmaxf(am + mag_b[n], 0.f);
  float ph = 6.28318530718f / (1.f + __expf(-(ap + phase_b[n])));
  float sp, cp;
  __sincosf(ph, &sp, &cp);
  *(float2*)(nf + idx * 2) = make_float2(m * cp, m * sp);
}

// ---------- K4: gate GEMM partials. C(2048 x 320) = A(2048 x 16448) * B.
// Block: M=64, N=160 (N-split), 256 thr / 4 waves (2m x 5n each).
// grid (32 mt, 2 nh, 8 sp) = 512 blocks -> 2 blocks/CU. Prefetch for i+1 is
// issued AFTER barrier 2 so it overlaps the MFMA phase (not drained by it).
__global__ __launch_bounds__(256, 2) void k_gemm(const float* __restrict__ fftc,
                                                 const float* __restrict__ W_proj,
                                                 const float* __restrict__ b_proj,
                                                 const unsigned short* __restrict__ wgt,
                                                 unsigned short* __restrict__ gpart) {
  __shared__ __align__(16) unsigned short As[64 * 72];
  __shared__ __align__(16) unsigned short Bs[160 * 72];
  const int tid = threadIdx.x;
  const int mt = blockIdx.x, nh = blockIdx.y, sp = blockIdx.z;
  const int i0 = (NF_ * sp) / SPK, i1 = (NF_ * (sp + 1)) / SPK;

  // A staging role: rows {rp, rp+32}, h-chunk hg*8..+8
  const int rp = tid >> 3, hg = tid & 7;
  float w0[8], w1[8], w2[8], w3[8], bpv[8];
#pragma unroll
  for (int j = 0; j < 8; ++j) {
    int h = hg * 8 + j;
    w0[j] = W_proj[h];       w1[j] = W_proj[64 + h];
    w2[j] = W_proj[128 + h]; w3[j] = W_proj[192 + h];
    bpv[j] = b_proj[h];
  }
  const int gm1 = mt * 64 + rp, gm2 = gm1 + 32;
  const int bb1 = gm1 >> 4, ff1 = gm1 & 15;
  const int bb2 = gm2 >> 4, ff2 = gm2 & 15;
  // B staging role: rows {nb + 32q, q<5} of this N-half, k-chunk part*8..+8
  const int nb = tid >> 3, part = tid & 7;
  const unsigned short* bbase = wgt + (nh * 160 + nb) * KDIM + part * 8;

  const int lane = tid & 63, wave = tid >> 6;
  const int wm = wave & 1, wn = wave >> 1;
  const int l15 = lane & 15, quad = lane >> 4;

  floatx4 acc[2][5];
#pragma unroll
  for (int a = 0; a < 2; ++a)
#pragma unroll
    for (int b = 0; b < 5; ++b) acc[a][b] = (floatx4){0.f, 0.f, 0.f, 0.f};

  // preamble: load i0 raw data into regs
  uint4 bv[5];
#pragma unroll
  for (int q = 0; q < 5; ++q)
    bv[q] = *(const uint4*)(bbase + q * (32 * KDIM) + i0 * 64);
  float2 z1 = *(const float2*)(fftc + ((bb1 * NF_ + i0) * 16 + ff1) * 2);
  float2 z2 = *(const float2*)(fftc + ((bb2 * NF_ + i0) * 16 + ff2) * 2);

  for (int i = i0; i < i1; ++i) {
    // features+pack for current i (z loaded last iteration -> latency hidden)
    float fr = (float)i * 0.1953125f;
    float d1 = z1.x * z1.x + z1.y * z1.y;
    float ir1 = d1 > 0.f ? rsqrtf(d1) : 0.f;
    float mag1 = d1 * ir1, sn1 = z1.y * ir1, cs1 = d1 > 0.f ? z1.x * ir1 : 1.f;
    float d2 = z2.x * z2.x + z2.y * z2.y;
    float ir2 = d2 > 0.f ? rsqrtf(d2) : 0.f;
    float mag2 = d2 * ir2, sn2 = z2.y * ir2, cs2 = d2 > 0.f ? z2.x * ir2 : 1.f;
    unsigned int pk1[4], pk2[4];
#pragma unroll
    for (int jj = 0; jj < 4; ++jj) {
      float p0 = fmaf(mag1, w0[2 * jj], fmaf(sn1, w1[2 * jj],
                 fmaf(cs1, w2[2 * jj], fmaf(fr, w3[2 * jj], bpv[2 * jj]))));
      float p1 = fmaf(mag1, w0[2 * jj + 1], fmaf(sn1, w1[2 * jj + 1],
                 fmaf(cs1, w2[2 * jj + 1], fmaf(fr, w3[2 * jj + 1], bpv[2 * jj + 1]))));
      float q0 = fmaf(mag2, w0[2 * jj], fmaf(sn2, w1[2 * jj],
                 fmaf(cs2, w2[2 * jj], fmaf(fr, w3[2 * jj], bpv[2 * jj]))));
      float q1 = fmaf(mag2, w0[2 * jj + 1], fmaf(sn2, w1[2 * jj + 1],
                 fmaf(cs2, w2[2 * jj + 1], fmaf(fr, w3[2 * jj + 1], bpv[2 * jj + 1]))));
      p0 = fmaxf(p0, 0.f); p1 = fmaxf(p1, 0.f);
      q0 = fmaxf(q0, 0.f); q1 = fmaxf(q1, 0.f);
      pk1[jj] = f2bf(p0) | (f2bf(p1) << 16);
      pk2[jj] = f2bf(q0) | (f2bf(q1) << 16);
    }
    __syncthreads();  // previous iteration's fragment reads complete
    *(uint4*)&As[rp * 72 + hg * 8] = make_uint4(pk1[0], pk1[1], pk1[2], pk1[3]);
    *(uint4*)&As[(rp + 32) * 72 + hg * 8] = make_uint4(pk2[0], pk2[1], pk2[2], pk2[3]);
#pragma unroll
    for (int q = 0; q < 5; ++q)
      *(uint4*)&Bs[(nb + 32 * q) * 72 + part * 8] = bv[q];
    __syncthreads();
    // prefetch i+1 NOW — overlaps the MFMA phase below; first consumption is
    // the feature VALU at the top of the next iteration (before any barrier).
    {
      const int ix = (i + 1 < i1) ? i + 1 : i;
#pragma unroll
      for (int q = 0; q < 5; ++q)
        bv[q] = *(const uint4*)(bbase + q * (32 * KDIM) + ix * 64);
      z1 = *(const float2*)(fftc + ((bb1 * NF_ + ix) * 16 + ff1) * 2);
      z2 = *(const float2*)(fftc + ((bb2 * NF_ + ix) * 16 + ff2) * 2);
    }
#pragma unroll
    for (int kh = 0; kh < 64; kh += 32) {
      short8 af[2];
#pragma unroll
      for (int mi = 0; mi < 2; ++mi)
        af[mi] = *(const short8*)&As[(wm * 32 + mi * 16 + l15) * 72 + kh + quad * 8];
#pragma unroll
      for (int ni = 0; ni < 5; ++ni) {
        short8 bfv = *(const short8*)&Bs[(wn * 80 + ni * 16 + l15) * 72 + kh + quad * 8];
#pragma unroll
        for (int mi = 0; mi < 2; ++mi)
          acc[mi][ni] = __builtin_amdgcn_mfma_f32_16x16x32_bf16(af[mi], bfv,
                                                                acc[mi][ni], 0, 0, 0);
      }
    }
  }
  unsigned short* gp = gpart + sp * (2048 * NPAD);
#pragma unroll
  for (int mi = 0; mi < 2; ++mi)
#pragma unroll
    for (int ni = 0; ni < 5; ++ni)
#pragma unroll
      for (int r = 0; r < 4; ++r) {
        int row = mt * 64 + wm * 32 + mi * 16 + quad * 4 + r;
        int col = nh * 160 + wn * 80 + ni * 16 + l15;
        gp[row * NPAD + col] = (unsigned short)f2bf(acc[mi][ni][r]);
      }
}

// ---------- K4r: sum split-K bf16 partials + bias -> SiLU -> sigmoid -> w
__global__ __launch_bounds__(256) void k_wred(const unsigned short* __restrict__ gpart,
                                              const float* __restrict__ b_gate,
                                              float* __restrict__ wbuf) {
  const int m = blockIdx.x;
  for (int n = threadIdx.x; n < NF_; n += 256) {
    float g = b_gate[n];
#pragma unroll
    for (int s2 = 0; s2 < SPK; ++s2)
      g += bf2f(gpart[s2 * (2048 * NPAD) + m * NPAD + n]);
    float sg = 1.f / (1.f + __expf(-g));
    float gs = g * sg;
    wbuf[m * NF_ + n] = 1.f / (1.f + __expf(-gs));
  }
}

// ---------- K5: blend + ortho-irfft (rotation recurrence) + residual + LayerNorm
// grid (4,128): bh = t-quarter (128 t), bb = batch. 256 thr = 128 t x 2 f-halves.
__global__ __launch_bounds__(256) void k_recon(const float* __restrict__ fftc,
                                               const float* __restrict__ nf,
                                               const float* __restrict__ wbuf,
                                               const float* __restrict__ x,
                                               const float* __restrict__ ln_g,
                                               const float* __restrict__ ln_b,
                                               float* __restrict__ out) {
  __shared__ float wfs[NF_ * 32];  // [k][f][2], Hermitian x2 folded in
  __shared__ float ls1[256], ls2[256];
  const int tid = threadIdx.x, bh = blockIdx.x, bb = blockIdx.y;
  for (int idx = tid; idx < NF_ * 16; idx += 256) {
    int k = idx >> 4, f = idx & 15;
    float2 fz = *(const float2*)(fftc + (bb * (NF_ * 16) + idx) * 2);
    float2 nz = *(const float2*)(nf + (bb * (NF_ * 16) + idx) * 2);
    float wv = wbuf[(bb * 16 + f) * NF_ + k];
    float sc = (k == 0 || k == 256) ? 1.f : 2.f;
    wfs[k * 32 + f * 2] = sc * (fz.x + wv * (nz.x - fz.x));
    wfs[k * 32 + f * 2 + 1] = sc * (fz.y + wv * (nz.y - fz.y));
  }
  __syncthreads();
  const int t = bh * 128 + (tid & 127), fh = tid >> 7;
  float sth, cth;
  __sincosf((float)t * 0.01227184630f, &sth, &cth);
  float c = 1.f, s = 0.f;
  float acc[8];
#pragma unroll
  for (int j = 0; j < 8; ++j) acc[j] = 0.f;
  const float4* wp4 = (const float4*)wfs;
  for (int k = 0; k < NF_; ++k) {
    float4 v0 = wp4[k * 8 + fh * 4 + 0];   // broadcast reads (k uniform per wave)
    float4 v1 = wp4[k * 8 + fh * 4 + 1];
    float4 v2 = wp4[k * 8 + fh * 4 + 2];
    float4 v3 = wp4[k * 8 + fh * 4 + 3];
    acc[0] = fmaf(v0.x, c, acc[0]); acc[0] = fmaf(-v0.y, s, acc[0]);
    acc[1] = fmaf(v0.z, c, acc[1]); acc[1] = fmaf(-v0.w, s, acc[1]);
    acc[2] = fmaf(v1.x, c, acc[2]); acc[2] = fmaf(-v1.y, s, acc[2]);
    acc[3] = fmaf(v1.z, c, acc[3]); acc[3] = fmaf(-v1.w, s, acc[3]);
    acc[4] = fmaf(v2.x, c, acc[4]); acc[4] = fmaf(-v2.y, s, acc[4]);
    acc[5] = fmaf(v2.z, c, acc[5]); acc[5] = fmaf(-v2.w, s, acc[5]);
    acc[6] = fmaf(v3.x, c, acc[6]); acc[6] = fmaf(-v3.y, s, acc[6]);
    acc[7] = fmaf(v3.z, c, acc[7]); acc[7] = fmaf(-v3.w, s, acc[7]);
    float nc = fmaf(c, cth, -s * sth);
    s = fmaf(s, cth, c * sth);
    c = nc;
  }
  const float S = 0.04419417382f;
  const float* xr = x + (bb * 512 + t) * 16 + fh * 8;
  float4 xa = *(const float4*)xr, xb = *(const float4*)(xr + 4);
  float y[8];
  y[0] = fmaf(acc[0], S, xa.x); y[1] = fmaf(acc[1], S, xa.y);
  y[2] = fmaf(acc[2], S, xa.z); y[3] = fmaf(acc[3], S, xa.w);
  y[4] = fmaf(acc[4], S, xb.x); y[5] = fmaf(acc[5], S, xb.y);
  y[6] = fmaf(acc[6], S, xb.z); y[7] = fmaf(acc[7], S, xb.w);
  float s1 = 0.f, s2 = 0.f;
#pragma unroll
  for (int j = 0; j < 8; ++j) { s1 += y[j]; s2 = fmaf(y[j], y[j], s2); }
  ls1[tid] = s1; ls2[tid] = s2;
  __syncthreads();
  const int o = tid ^ 128;
  float t1 = s1 + ls1[o], t2 = s2 + ls2[o];
  float mu = t1 * 0.0625f;
  float var = t2 * 0.0625f - mu * mu;
  float rs = rsqrtf(var + 1e-5f);
  float* orow = out + (bb * 512 + t) * 16 + fh * 8;
  float4 o0, o1;
  o0.x = (y[0] - mu) * rs * ln_g[fh * 8 + 0] + ln_b[fh * 8 + 0];
  o0.y = (y[1] - mu) * rs * ln_g[fh * 8 + 1] + ln_b[fh * 8 + 1];
  o0.z = (y[2] - mu) * rs * ln_g[fh * 8 + 2] + ln_b[fh * 8 + 2];
  o0.w = (y[3] - mu) * rs * ln_g[fh * 8 + 3] + ln_b[fh * 8 + 3];
  o1.x = (y[4] - mu) * rs * ln_g[fh * 8 + 4] + ln_b[fh * 8 + 4];
  o1.y = (y[5] - mu) * rs * ln_g[fh * 8 + 5] + ln_b[fh * 8 + 5];
  o1.z = (y[6] - mu) * rs * ln_g[fh * 8 + 6] + ln_b[fh * 8 + 6];
  o1.w = (y[7] - mu) * rs * ln_g[fh * 8 + 7] + ln_b[fh * 8 + 7];
  *(float4*)orow = o0;
  *(float4*)(orow + 4) = o1;
}

extern "C" void kernel_launch(void* const* d_in, const int* in_sizes, int n_in,
                              void* d_out, int out_size, void* d_ws, size_t ws_size,
                              hipStream_t stream) {
  const float* x = (const float*)d_in[0];
  const float* W_proj = (const float*)d_in[1];
  const float* b_proj = (const float*)d_in[2];
  const float* W_gate = (const float*)d_in[3];
  const float* b_gate = (const float*)d_in[4];
  const float* mag_w = (const float*)d_in[5];
  const float* mag_b = (const float*)d_in[6];
  const float* phase_w = (const float*)d_in[7];
  const float* phase_b = (const float*)d_in[8];
  const float* ln_g = (const float*)d_in[9];
  const float* ln_b = (const float*)d_in[10];
  float* out = (float*)d_out;
  float* ws = (float*)d_ws;

  // workspace layout (float slots): 7,950,592 = 31.8 MB (proven cap)
  float* csd = ws;                                        //    65,792
  float* fftc = ws + 65792;                               // 1,052,672
  float* nf = ws + 1118464;                               // 1,052,672
  float* wbuf = ws + 2171136;                             //   526,336
  unsigned short* gpart = (unsigned short*)(ws + 2697472);// SPK*2048*320 bf16
  unsigned short* wgt = (unsigned short*)(ws + 5318912);  // 320*16448 bf16

  hipLaunchKernelGGL(k_wgt, dim3(514, 10), dim3(256), 0, stream, W_gate, wgt);
  hipLaunchKernelGGL(k_csd, dim3(128), dim3(256), 0, stream, x, csd);
  hipLaunchKernelGGL(k_fft, dim3(4, 128), dim3(256), 0, stream, x, csd, fftc);
  hipLaunchKernelGGL(k_new, dim3(2056), dim3(256), 0, stream, fftc, W_proj, b_proj,
                     mag_w, mag_b, phase_w, phase_b, nf);
  hipLaunchKernelGGL(k_gemm, dim3(32, 2, SPK), dim3(256), 0, stream, fftc, W_proj,
                     b_proj, wgt, gpart);
  hipLaunchKernelGGL(k_wred, dim3(2048), dim3(256), 0, stream, gpart, b_gate, wbuf);
  hipLaunchKernelGGL(k_recon, dim3(4, 128), dim3(256), 0, stream, fftc, nf, wbuf, x,
                     ln_g, ln_b, out);
}

// Round 5
// 304.541 us; speedup vs baseline: 1.1215x; 1.1215x over previous
//
#include <hip/hip_runtime.h>

// AdaptiveSpectrumLayer: B=128, H=T=512, F=16, HID=64, NF=257
// v4: k_gemm: fftc slice cached in LDS (no global loads in K-loop except B),
// fragment-major LDS (conflict-free ds_read_b128), XCD-clustered block swizzle
// (wgt slices pinned per-XCD L2), block-exclusive gpart regions (no RMW).
// k_wgt: full-line writes. k_csd: DFT split over 2 blocks/batch.

#define NF_ 257
#define KDIM 16448   // NF_*64
#define SPK 8

typedef __attribute__((ext_vector_type(8))) short short8;
typedef __attribute__((ext_vector_type(4))) float floatx4;

__device__ __forceinline__ unsigned int f2bf(float x) {
  union { float f; unsigned int u; } v; v.f = x;
  return (v.u + 0x7FFFu + ((v.u >> 16) & 1u)) >> 16;
}
__device__ __forceinline__ float bf2f(unsigned short u) {
  union { unsigned int u; float f; } v; v.u = ((unsigned int)u) << 16;
  return v.f;
}

// ---------- K0: W_gate (16448 x 257 f32) -> wgt bf16 transposed (320 x 16448)
// 64k x 32n tiles: store phase writes 128B full lines per row.
__global__ __launch_bounds__(256) void k_wgt(const float* __restrict__ Wg,
                                             unsigned short* __restrict__ wgt) {
  __shared__ float tile[64][33];
  const int tid = threadIdx.x;
  const int k0 = blockIdx.x * 64, n0 = blockIdx.y * 32;
  const int c = tid & 31, r8 = tid >> 5;
  const int n = n0 + c;
#pragma unroll
  for (int j = 0; j < 8; ++j) {
    int rr = r8 + j * 8;
    tile[rr][c] = (n < NF_) ? Wg[(k0 + rr) * NF_ + n] : 0.f;
  }
  __syncthreads();
  const int c64 = tid & 63, n4 = tid >> 6;
#pragma unroll
  for (int j = 0; j < 8; ++j) {
    int nn = n4 + j * 4;
    wgt[(n0 + nn) * KDIM + k0 + c64] = (unsigned short)f2bf(tile[c64][nn]);
  }
}

// ---------- K1: csd[b][k] = (1/(256*sqrt(512))) * DFT_t( autocorr(s)[t-255] )
// grid (2,128): bh = bin-half (redundant autocorr), bb = batch.
__global__ __launch_bounds__(256) void k_csd(const float* __restrict__ x,
                                             float* __restrict__ csd) {
  __shared__ float sl[768];   // [0,512) data, [512,768) zeros
  __shared__ float ac[257];
  __shared__ float red[4];
  const int tid = threadIdx.x, bh = blockIdx.x, bb = blockIdx.y;
  for (int t = tid; t < 768; t += 256) {
    float v = 0.f;
    if (t < 512) {
      const float4* xp = (const float4*)(x + (bb * 512 + t) * 16);
      float4 a = xp[0], c = xp[1], d = xp[2], e = xp[3];
      v = a.x + a.y + a.z + a.w + c.x + c.y + c.z + c.w +
          d.x + d.y + d.z + d.w + e.x + e.y + e.z + e.w;
    }
    sl[t] = v;
  }
  __syncthreads();
  {  // lag = tid (0..255): uniform-broadcast float4 + stride-1 lane reads
    float a0 = 0.f, a1 = 0.f, a2 = 0.f, a3 = 0.f;
    for (int tau = 0; tau < 512; tau += 4) {
      float4 u = *(const float4*)&sl[tau];
      a0 = fmaf(u.x, sl[tau + tid], a0);
      a1 = fmaf(u.y, sl[tau + tid + 1], a1);
      a2 = fmaf(u.z, sl[tau + tid + 2], a2);
      a3 = fmaf(u.w, sl[tau + tid + 3], a3);
    }
    ac[tid] = (a0 + a1) + (a2 + a3);
  }
  {  // lag 256 via block reduce
    float p = sl[tid] * sl[tid + 256];
#pragma unroll
    for (int off = 32; off; off >>= 1) p += __shfl_down(p, off);
    if ((tid & 63) == 0) red[tid >> 6] = p;
  }
  __syncthreads();
  if (tid == 0) ac[256] = red[0] + red[1] + red[2] + red[3];
  __syncthreads();
  const float S1 = 0.04419417382f / 256.f;
  const int k = bh * 129 + tid;              // bh0: 0..128, bh1: 129..256
  const int kmax = (bh == 0) ? 129 : 128;
  if (tid < kmax) {
    float sth, cth;
    __sincosf((float)k * 0.01227184630f, &sth, &cth);  // 2*pi/512
    float c = 1.f, s = 0.f, re = 0.f, im = 0.f;
    for (int t = 0; t < 512; ++t) {
      int d = t - 255;
      float ov = ac[d < 0 ? -d : d];         // uniform broadcast
      re = fmaf(ov, c, re);
      im = fmaf(-ov, s, im);
      float nc = fmaf(c, cth, -s * sth);
      s = fmaf(s, cth, c * sth);
      c = nc;
    }
    *(float2*)(csd + (bb * NF_ + k) * 2) = make_float2(re * S1, im * S1);
  }
}

// ---------- K2: fftc[b][k][f] = ortho-rfft(x)[k,f] + csd[b][k]
__global__ __launch_bounds__(256) void k_fft(const float* __restrict__ x,
                                             const float* __restrict__ csd,
                                             float* __restrict__ fftc) {
  __shared__ float xs[512 * 4];
  __shared__ float red[4][4];
  const int tid = threadIdx.x, fq = blockIdx.x, bb = blockIdx.y;
  for (int t = tid; t < 512; t += 256)
    *(float4*)&xs[t * 4] = *(const float4*)(x + (bb * 512 + t) * 16 + fq * 4);
  __syncthreads();
  const int k = tid;
  float sth, cth;
  __sincosf((float)k * 0.01227184630f, &sth, &cth);
  float c = 1.f, s = 0.f;
  float re0 = 0.f, re1 = 0.f, re2 = 0.f, re3 = 0.f;
  float im0 = 0.f, im1 = 0.f, im2 = 0.f, im3 = 0.f;
  for (int t = 0; t < 512; ++t) {
    float4 xv = *(const float4*)&xs[t * 4];   // broadcast
    re0 = fmaf(xv.x, c, re0); im0 = fmaf(-xv.x, s, im0);
    re1 = fmaf(xv.y, c, re1); im1 = fmaf(-xv.y, s, im1);
    re2 = fmaf(xv.z, c, re2); im2 = fmaf(-xv.z, s, im2);
    re3 = fmaf(xv.w, c, re3); im3 = fmaf(-xv.w, s, im3);
    float nc = fmaf(c, cth, -s * sth);
    s = fmaf(s, cth, c * sth);
    c = nc;
  }
  const float S = 0.04419417382f;  // 1/sqrt(512)
  float2 cz = *(const float2*)(csd + (bb * NF_ + k) * 2);
  float* o = fftc + ((bb * NF_ + k) * 16 + fq * 4) * 2;
  o[0] = re0 * S + cz.x; o[1] = im0 * S + cz.y;
  o[2] = re1 * S + cz.x; o[3] = im1 * S + cz.y;
  o[4] = re2 * S + cz.x; o[5] = im2 * S + cz.y;
  o[6] = re3 * S + cz.x; o[7] = im3 * S + cz.y;
  const int t0 = tid * 2;
  float p0 = xs[t0 * 4 + 0] - xs[t0 * 4 + 4];
  float p1 = xs[t0 * 4 + 1] - xs[t0 * 4 + 5];
  float p2 = xs[t0 * 4 + 2] - xs[t0 * 4 + 6];
  float p3 = xs[t0 * 4 + 3] - xs[t0 * 4 + 7];
#pragma unroll
  for (int off = 32; off; off >>= 1) {
    p0 += __shfl_down(p0, off);
    p1 += __shfl_down(p1, off);
    p2 += __shfl_down(p2, off);
    p3 += __shfl_down(p3, off);
  }
  if ((tid & 63) == 0) {
    red[tid >> 6][0] = p0; red[tid >> 6][1] = p1;
    red[tid >> 6][2] = p2; red[tid >> 6][3] = p3;
  }
  __syncthreads();
  if (tid == 0) {
    float2 cz2 = *(const float2*)(csd + (bb * NF_ + 256) * 2);
#pragma unroll
    for (int j = 0; j < 4; ++j) {
      float r = red[0][j] + red[1][j] + red[2][j] + red[3][j];
      float* oo = fftc + ((bb * NF_ + 256) * 16 + fq * 4 + j) * 2;
      oo[0] = r * S + cz2.x;
      oo[1] = cz2.y;
    }
  }
}

// ---------- K3: new_fft[b][n][f] from recomputed proj + per-freq complexifier
__global__ __launch_bounds__(256) void k_new(const float* __restrict__ fftc,
                                             const float* __restrict__ W_proj,
                                             const float* __restrict__ b_proj,
                                             const float* __restrict__ mag_w,
                                             const float* __restrict__ mag_b,
                                             const float* __restrict__ phase_w,
                                             const float* __restrict__ phase_b,
                                             float* __restrict__ nf) {
  __shared__ float wp[256], bp[64];
  const int tid = threadIdx.x;
  wp[tid] = W_proj[tid];
  if (tid < 64) bp[tid] = b_proj[tid];
  __syncthreads();
  const int idx = blockIdx.x * 256 + tid;
  const int bn = idx >> 4;
  const int n = bn % NF_;
  float2 z = *(const float2*)(fftc + idx * 2);
  float d = z.x * z.x + z.y * z.y;
  float ir = d > 0.f ? rsqrtf(d) : 0.f;
  float mag = d * ir;
  float sn = z.y * ir;
  float cs = d > 0.f ? z.x * ir : 1.f;
  float fr = (float)n * 0.1953125f;  // 100/512
  float am = 0.f, ap = 0.f;
#pragma unroll 8
  for (int h = 0; h < 64; ++h) {
    float p = fmaf(mag, wp[h], fmaf(sn, wp[64 + h], fmaf(cs, wp[128 + h],
              fmaf(fr, wp[192 + h], bp[h]))));
    p = fmaxf(p, 0.f);
    am = fmaf(p, mag_w[n * 64 + h], am);
    ap = fmaf(p, phase_w[n * 64 + h], ap);
  }
  float m = fmaxf(am + mag_b[n], 0.f);
  float ph = 6.28318530718f / (1.f + __expf(-(ap + phase_b[n])));
  float sp, cp;
  __sincosf(ph, &sp, &cp);
  *(float2*)(nf + idx * 2) = make_float2(m * cp, m * sp);
}

// ---------- K4: gate GEMM. C(2048x320) = A(2048x16448) * B^T, A recomputed.
// Block: M=64, N=160 (nh halves), split-K=8. 512 blocks, 2/CU.
// XCD swizzle: all 32 mt-blocks of one (nh,sp) share bid%8 -> same XCD L2.
// LDS: zs (fftc slice), As2/Bs2 fragment-major (conflict-free b128 reads).
__global__ __launch_bounds__(256, 2) void k_gemm(const float* __restrict__ fftc,
                                                 const float* __restrict__ W_proj,
                                                 const float* __restrict__ b_proj,
                                                 const unsigned short* __restrict__ wgt,
                                                 unsigned short* __restrict__ gpart) {
  __shared__ __align__(16) unsigned short As2[8 * 64 * 8];    //  8 KB [kq][m][8]
  __shared__ __align__(16) unsigned short Bs2[8 * 160 * 8];   // 20 KB [kq][n][8]
  __shared__ float2 zs[64 * 33];                              // 17 KB [m][ii]
  const int tid = threadIdx.x;
  const int bid = blockIdx.x;
  const int xcd = bid & 7, j = bid >> 3;       // j in [0,64)
  const int mt = j & 31;
  const int slice = xcd * 2 + (j >> 5);        // [0,16)
  const int sp = slice >> 1, nh = slice & 1;
  const int i0 = (NF_ * sp) / SPK, i1 = (NF_ * (sp + 1)) / SPK;
  const int ni = i1 - i0;

  // A producer role: rows {rp, rp+32}, h-chunk hg*8..+8
  const int rp = tid >> 3, hg = tid & 7;
  float w0[8], w1[8], w2[8], w3[8], bpv[8];
#pragma unroll
  for (int jj = 0; jj < 8; ++jj) {
    int h = hg * 8 + jj;
    w0[jj] = W_proj[h];       w1[jj] = W_proj[64 + h];
    w2[jj] = W_proj[128 + h]; w3[jj] = W_proj[192 + h];
    bpv[jj] = b_proj[h];
  }
  // B producer role: n rows {nb2 + 32q}, k-chunk kq*8..+8
  const int nb2 = tid >> 3, kq = tid & 7;
  const unsigned short* bbase = wgt + (nh * 160 + nb2) * KDIM + kq * 8;

  const int lane = tid & 63, wave = tid >> 6;
  const int wm = wave & 1, wn = wave >> 1;
  const int l15 = lane & 15, quad = lane >> 4;

  floatx4 acc[2][5];
#pragma unroll
  for (int a = 0; a < 2; ++a)
#pragma unroll
    for (int b = 0; b < 5; ++b) acc[a][b] = (floatx4){0.f, 0.f, 0.f, 0.f};

  // prefetch B(i0) into regs, then stage fftc slice into LDS
  uint4 bv[5];
#pragma unroll
  for (int q = 0; q < 5; ++q)
    bv[q] = *(const uint4*)(bbase + q * (32 * KDIM) + i0 * 64);
  for (int li = tid; li < 64 * ni; li += 256) {
    int r = li & 63, ii = li >> 6;
    int gm = mt * 64 + r;
    zs[r * 33 + ii] =
        *(const float2*)(fftc + (((gm >> 4) * NF_ + i0 + ii) * 16 + (gm & 15)) * 2);
  }
  __syncthreads();

  for (int i = i0; i < i1; ++i) {
    const int ii = i - i0;
    float2 z1 = zs[rp * 33 + ii];
    float2 z2 = zs[(rp + 32) * 33 + ii];
    float fr = (float)i * 0.1953125f;
    float d1 = z1.x * z1.x + z1.y * z1.y;
    float ir1 = d1 > 0.f ? rsqrtf(d1) : 0.f;
    float mag1 = d1 * ir1, sn1 = z1.y * ir1, cs1 = d1 > 0.f ? z1.x * ir1 : 1.f;
    float d2 = z2.x * z2.x + z2.y * z2.y;
    float ir2 = d2 > 0.f ? rsqrtf(d2) : 0.f;
    float mag2 = d2 * ir2, sn2 = z2.y * ir2, cs2 = d2 > 0.f ? z2.x * ir2 : 1.f;
    unsigned int pk1[4], pk2[4];
#pragma unroll
    for (int jj = 0; jj < 4; ++jj) {
      float p0 = fmaf(mag1, w0[2 * jj], fmaf(sn1, w1[2 * jj],
                 fmaf(cs1, w2[2 * jj], fmaf(fr, w3[2 * jj], bpv[2 * jj]))));
      float p1 = fmaf(mag1, w0[2 * jj + 1], fmaf(sn1, w1[2 * jj + 1],
                 fmaf(cs1, w2[2 * jj + 1], fmaf(fr, w3[2 * jj + 1], bpv[2 * jj + 1]))));
      float q0 = fmaf(mag2, w0[2 * jj], fmaf(sn2, w1[2 * jj],
                 fmaf(cs2, w2[2 * jj], fmaf(fr, w3[2 * jj], bpv[2 * jj]))));
      float q1 = fmaf(mag2, w0[2 * jj + 1], fmaf(sn2, w1[2 * jj + 1],
                 fmaf(cs2, w2[2 * jj + 1], fmaf(fr, w3[2 * jj + 1], bpv[2 * jj + 1]))));
      p0 = fmaxf(p0, 0.f); p1 = fmaxf(p1, 0.f);
      q0 = fmaxf(q0, 0.f); q1 = fmaxf(q1, 0.f);
      pk1[jj] = f2bf(p0) | (f2bf(p1) << 16);
      pk2[jj] = f2bf(q0) | (f2bf(q1) << 16);
    }
    __syncthreads();  // prior iteration's fragment reads complete
    *(uint4*)&As2[(hg * 64 + rp) * 8] = make_uint4(pk1[0], pk1[1], pk1[2], pk1[3]);
    *(uint4*)&As2[(hg * 64 + rp + 32) * 8] = make_uint4(pk2[0], pk2[1], pk2[2], pk2[3]);
#pragma unroll
    for (int q = 0; q < 5; ++q)
      *(uint4*)&Bs2[(kq * 160 + nb2 + 32 * q) * 8] = bv[q];
    __syncthreads();
    // prefetch B(i+1): overlaps MFMA below + features at top of next iter
    {
      const int ix = (i + 1 < i1) ? i + 1 : i;
#pragma unroll
      for (int q = 0; q < 5; ++q)
        bv[q] = *(const uint4*)(bbase + q * (32 * KDIM) + ix * 64);
    }
#pragma unroll
    for (int kh = 0; kh < 2; ++kh) {
      short8 af[2];
#pragma unroll
      for (int mi = 0; mi < 2; ++mi)
        af[mi] = *(const short8*)
            &As2[((kh * 4 + quad) * 64 + wm * 32 + mi * 16 + l15) * 8];
#pragma unroll
      for (int nn = 0; nn < 5; ++nn) {
        short8 bfv = *(const short8*)
            &Bs2[((kh * 4 + quad) * 160 + wn * 80 + nn * 16 + l15) * 8];
#pragma unroll
        for (int mi = 0; mi < 2; ++mi)
          acc[mi][nn] = __builtin_amdgcn_mfma_f32_16x16x32_bf16(af[mi], bfv,
                                                                acc[mi][nn], 0, 0, 0);
      }
    }
  }
  // epilogue: block-exclusive region [slice][2048][160] -> no RMW sharing
  unsigned short* gp = gpart + (size_t)slice * (2048 * 160);
#pragma unroll
  for (int mi = 0; mi < 2; ++mi)
#pragma unroll
    for (int nn = 0; nn < 5; ++nn)
#pragma unroll
      for (int r = 0; r < 4; ++r) {
        int row = mt * 64 + wm * 32 + mi * 16 + quad * 4 + r;
        int col = wn * 80 + nn * 16 + l15;
        gp[row * 160 + col] = (unsigned short)f2bf(acc[mi][nn][r]);
      }
}

// ---------- K4r: sum split-K bf16 partials + bias -> SiLU -> sigmoid -> w
__global__ __launch_bounds__(256) void k_wred(const unsigned short* __restrict__ gpart,
                                              const float* __restrict__ b_gate,
                                              float* __restrict__ wbuf) {
  const int m = blockIdx.x;
  for (int n = threadIdx.x; n < NF_; n += 256) {
    const int half = (n >= 160) ? 1 : 0;
    const int col = n - half * 160;
    float g = b_gate[n];
#pragma unroll
    for (int s2 = 0; s2 < SPK; ++s2)
      g += bf2f(gpart[((size_t)(s2 * 2 + half) * 2048 + m) * 160 + col]);
    float sg = 1.f / (1.f + __expf(-g));
    float gs = g * sg;
    wbuf[m * NF_ + n] = 1.f / (1.f + __expf(-gs));
  }
}

// ---------- K5: blend + ortho-irfft (rotation recurrence) + residual + LayerNorm
__global__ __launch_bounds__(256) void k_recon(const float* __restrict__ fftc,
                                               const float* __restrict__ nf,
                                               const float* __restrict__ wbuf,
                                               const float* __restrict__ x,
                                               const float* __restrict__ ln_g,
                                               const float* __restrict__ ln_b,
                                               float* __restrict__ out) {
  __shared__ float wfs[NF_ * 32];  // [k][f][2], Hermitian x2 folded in
  __shared__ float ls1[256], ls2[256];
  const int tid = threadIdx.x, bh = blockIdx.x, bb = blockIdx.y;
  for (int idx = tid; idx < NF_ * 16; idx += 256) {
    int k = idx >> 4, f = idx & 15;
    float2 fz = *(const float2*)(fftc + (bb * (NF_ * 16) + idx) * 2);
    float2 nz = *(const float2*)(nf + (bb * (NF_ * 16) + idx) * 2);
    float wv = wbuf[(bb * 16 + f) * NF_ + k];
    float sc = (k == 0 || k == 256) ? 1.f : 2.f;
    wfs[k * 32 + f * 2] = sc * (fz.x + wv * (nz.x - fz.x));
    wfs[k * 32 + f * 2 + 1] = sc * (fz.y + wv * (nz.y - fz.y));
  }
  __syncthreads();
  const int t = bh * 128 + (tid & 127), fh = tid >> 7;
  float sth, cth;
  __sincosf((float)t * 0.01227184630f, &sth, &cth);
  float c = 1.f, s = 0.f;
  float acc[8];
#pragma unroll
  for (int j = 0; j < 8; ++j) acc[j] = 0.f;
  const float4* wp4 = (const float4*)wfs;
  for (int k = 0; k < NF_; ++k) {
    float4 v0 = wp4[k * 8 + fh * 4 + 0];
    float4 v1 = wp4[k * 8 + fh * 4 + 1];
    float4 v2 = wp4[k * 8 + fh * 4 + 2];
    float4 v3 = wp4[k * 8 + fh * 4 + 3];
    acc[0] = fmaf(v0.x, c, acc[0]); acc[0] = fmaf(-v0.y, s, acc[0]);
    acc[1] = fmaf(v0.z, c, acc[1]); acc[1] = fmaf(-v0.w, s, acc[1]);
    acc[2] = fmaf(v1.x, c, acc[2]); acc[2] = fmaf(-v1.y, s, acc[2]);
    acc[3] = fmaf(v1.z, c, acc[3]); acc[3] = fmaf(-v1.w, s, acc[3]);
    acc[4] = fmaf(v2.x, c, acc[4]); acc[4] = fmaf(-v2.y, s, acc[4]);
    acc[5] = fmaf(v2.z, c, acc[5]); acc[5] = fmaf(-v2.w, s, acc[5]);
    acc[6] = fmaf(v3.x, c, acc[6]); acc[6] = fmaf(-v3.w * 0.f - v3.y * 0.f - v3.y, s, acc[6]);
    acc[7] = fmaf(v3.z, c, acc[7]); acc[7] = fmaf(-v3.w, s, acc[7]);
    float nc = fmaf(c, cth, -s * sth);
    s = fmaf(s, cth, c * sth);
    c = nc;
  }
  const float S = 0.04419417382f;
  const float* xr = x + (bb * 512 + t) * 16 + fh * 8;
  float4 xa = *(const float4*)xr, xb = *(const float4*)(xr + 4);
  float y[8];
  y[0] = fmaf(acc[0], S, xa.x); y[1] = fmaf(acc[1], S, xa.y);
  y[2] = fmaf(acc[2], S, xa.z); y[3] = fmaf(acc[3], S, xa.w);
  y[4] = fmaf(acc[4], S, xb.x); y[5] = fmaf(acc[5], S, xb.y);
  y[6] = fmaf(acc[6], S, xb.z); y[7] = fmaf(acc[7], S, xb.w);
  float s1 = 0.f, s2 = 0.f;
#pragma unroll
  for (int j = 0; j < 8; ++j) { s1 += y[j]; s2 = fmaf(y[j], y[j], s2); }
  ls1[tid] = s1; ls2[tid] = s2;
  __syncthreads();
  const int o = tid ^ 128;
  float t1 = s1 + ls1[o], t2 = s2 + ls2[o];
  float mu = t1 * 0.0625f;
  float var = t2 * 0.0625f - mu * mu;
  float rs = rsqrtf(var + 1e-5f);
  float* orow = out + (bb * 512 + t) * 16 + fh * 8;
  float4 o0, o1;
  o0.x = (y[0] - mu) * rs * ln_g[fh * 8 + 0] + ln_b[fh * 8 + 0];
  o0.y = (y[1] - mu) * rs * ln_g[fh * 8 + 1] + ln_b[fh * 8 + 1];
  o0.z = (y[2] - mu) * rs * ln_g[fh * 8 + 2] + ln_b[fh * 8 + 2];
  o0.w = (y[3] - mu) * rs * ln_g[fh * 8 + 3] + ln_b[fh * 8 + 3];
  o1.x = (y[4] - mu) * rs * ln_g[fh * 8 + 4] + ln_b[fh * 8 + 4];
  o1.y = (y[5] - mu) * rs * ln_g[fh * 8 + 5] + ln_b[fh * 8 + 5];
  o1.z = (y[6] - mu) * rs * ln_g[fh * 8 + 6] + ln_b[fh * 8 + 6];
  o1.w = (y[7] - mu) * rs * ln_g[fh * 8 + 7] + ln_b[fh * 8 + 7];
  *(float4*)orow = o0;
  *(float4*)(orow + 4) = o1;
}

extern "C" void kernel_launch(void* const* d_in, const int* in_sizes, int n_in,
                              void* d_out, int out_size, void* d_ws, size_t ws_size,
                              hipStream_t stream) {
  const float* x = (const float*)d_in[0];
  const float* W_proj = (const float*)d_in[1];
  const float* b_proj = (const float*)d_in[2];
  const float* W_gate = (const float*)d_in[3];
  const float* b_gate = (const float*)d_in[4];
  const float* mag_w = (const float*)d_in[5];
  const float* mag_b = (const float*)d_in[6];
  const float* phase_w = (const float*)d_in[7];
  const float* phase_b = (const float*)d_in[8];
  const float* ln_g = (const float*)d_in[9];
  const float* ln_b = (const float*)d_in[10];
  float* out = (float*)d_out;
  float* ws = (float*)d_ws;

  // workspace layout (float slots): 7,950,592 = 31.8 MB (proven cap)
  float* csd = ws;                                        //    65,792
  float* fftc = ws + 65792;                               // 1,052,672
  float* nf = ws + 1118464;                               // 1,052,672
  float* wbuf = ws + 2171136;                             //   526,336
  unsigned short* gpart = (unsigned short*)(ws + 2697472);// 16*2048*160 bf16
  unsigned short* wgt = (unsigned short*)(ws + 5318912);  // 320*16448 bf16

  hipLaunchKernelGGL(k_wgt, dim3(257, 10), dim3(256), 0, stream, W_gate, wgt);
  hipLaunchKernelGGL(k_csd, dim3(2, 128), dim3(256), 0, stream, x, csd);
  hipLaunchKernelGGL(k_fft, dim3(4, 128), dim3(256), 0, stream, x, csd, fftc);
  hipLaunchKernelGGL(k_new, dim3(2056), dim3(256), 0, stream, fftc, W_proj, b_proj,
                     mag_w, mag_b, phase_w, phase_b, nf);
  hipLaunchKernelGGL(k_gemm, dim3(512), dim3(256), 0, stream, fftc, W_proj,
                     b_proj, wgt, gpart);
  hipLaunchKernelGGL(k_wred, dim3(2048), dim3(256), 0, stream, gpart, b_gate, wbuf);
  hipLaunchKernelGGL(k_recon, dim3(4, 128), dim3(256), 0, stream, fftc, nf, wbuf, x,
                     ln_g, ln_b, out);
}

// Round 6
// 267.203 us; speedup vs baseline: 1.2783x; 1.1397x over previous
//
#include <hip/hip_runtime.h>

// AdaptiveSpectrumLayer: B=128, H=T=512, F=16, HID=64, NF=257
// v5: k_gemm XOR-swizzled LDS (conflict-free writes+reads), 4m x 5n wave tiles,
// SPK=16, bf16 fftc cache. k_csd fused into k_fft (shared twiddle recurrence).
// DFT kernels chunked (float4-of-t, 4-phase rotation) for load ILP.

#define NF_ 257
#define KDIM 16448   // NF_*64
#define SPK 16

typedef __attribute__((ext_vector_type(8))) short short8;
typedef __attribute__((ext_vector_type(4))) float floatx4;

__device__ __forceinline__ unsigned int f2bf(float x) {
  union { float f; unsigned int u; } v; v.f = x;
  return (v.u + 0x7FFFu + ((v.u >> 16) & 1u)) >> 16;
}
__device__ __forceinline__ float bf2f(unsigned int u16) {
  union { unsigned int u; float f; } v; v.u = u16 << 16;
  return v.f;
}

// ---------- K0: W_gate (16448 x 257 f32) -> wgt bf16 transposed (320 x 16448)
__global__ __launch_bounds__(256) void k_wgt(const float* __restrict__ Wg,
                                             unsigned short* __restrict__ wgt) {
  __shared__ float tile[64][33];
  const int tid = threadIdx.x;
  const int k0 = blockIdx.x * 64, n0 = blockIdx.y * 32;
  const int c = tid & 31, r8 = tid >> 5;
  const int n = n0 + c;
#pragma unroll
  for (int j = 0; j < 8; ++j) {
    int rr = r8 + j * 8;
    tile[rr][c] = (n < NF_) ? Wg[(k0 + rr) * NF_ + n] : 0.f;
  }
  __syncthreads();
  const int c64 = tid & 63, n4 = tid >> 6;
#pragma unroll
  for (int j = 0; j < 8; ++j) {
    int nn = n4 + j * 4;
    wgt[(n0 + nn) * KDIM + k0 + c64] = (unsigned short)f2bf(tile[c64][nn]);
  }
}

// ---------- K1: fftc[b][k][f] = ortho-rfft(x)[k,f] + csd[b][k]  (csd fused)
// grid (4,128): fq = f-quartet, bb = batch. Thread = bin k. csd = DFT of the
// mirrored autocorr of the row-sum; shares the chunked twiddle recurrence.
__global__ __launch_bounds__(256) void k_fft(const float* __restrict__ x,
                                             float* __restrict__ fftc) {
  __shared__ float xs4[4 * 512];   // [f][t]
  __shared__ float sl[768];        // row-sum, zero-padded
  __shared__ float ac[257];
  __shared__ float ol[512];
  __shared__ float redl[4];
  __shared__ float red2[4][5];
  const int tid = threadIdx.x, fq = blockIdx.x, bb = blockIdx.y;
  for (int t = tid; t < 512; t += 256) {
    const float4* xp = (const float4*)(x + (bb * 512 + t) * 16);
    float4 a = xp[0], b = xp[1], c = xp[2], d = xp[3];
    sl[t] = a.x + a.y + a.z + a.w + b.x + b.y + b.z + b.w +
            c.x + c.y + c.z + c.w + d.x + d.y + d.z + d.w;
    float4 mine = (fq == 0) ? a : (fq == 1) ? b : (fq == 2) ? c : d;
    xs4[t] = mine.x;
    xs4[512 + t] = mine.y;
    xs4[1024 + t] = mine.z;
    xs4[1536 + t] = mine.w;
  }
  for (int t = 512 + tid; t < 768; t += 256) sl[t] = 0.f;
  __syncthreads();
  {  // autocorr lag = tid (0..255): broadcast float4 x stride-1 lanes
    float a0 = 0.f, a1 = 0.f, a2 = 0.f, a3 = 0.f;
    for (int tau = 0; tau < 512; tau += 4) {
      float4 u = *(const float4*)&sl[tau];
      a0 = fmaf(u.x, sl[tau + tid], a0);
      a1 = fmaf(u.y, sl[tau + tid + 1], a1);
      a2 = fmaf(u.z, sl[tau + tid + 2], a2);
      a3 = fmaf(u.w, sl[tau + tid + 3], a3);
    }
    ac[tid] = (a0 + a1) + (a2 + a3);
  }
  {  // lag 256
    float p = sl[tid] * sl[tid + 256];
#pragma unroll
    for (int off = 32; off; off >>= 1) p += __shfl_down(p, off);
    if ((tid & 63) == 0) redl[tid >> 6] = p;
  }
  __syncthreads();
  if (tid == 0) ac[256] = redl[0] + redl[1] + redl[2] + redl[3];
  __syncthreads();
  for (int t = tid; t < 512; t += 256) {
    int d = t - 255;
    ol[t] = ac[d < 0 ? -d : d];
  }
  __syncthreads();
  // DFT: bin k = tid, 128 chunks of 4 t, 4-phase rotation
  const int k = tid;
  const float th0 = (float)k * 0.01227184630f;  // 2*pi/512
  float c4, s4;
  __sincosf(4.f * th0, &s4, &c4);
  float cj[4], sj[4];
  cj[0] = 1.f; sj[0] = 0.f;
  __sincosf(th0, &sj[1], &cj[1]);
  __sincosf(2.f * th0, &sj[2], &cj[2]);
  __sincosf(3.f * th0, &sj[3], &cj[3]);
  float re[4] = {0.f, 0.f, 0.f, 0.f}, im[4] = {0.f, 0.f, 0.f, 0.f};
  float rec = 0.f, imc = 0.f;
  for (int m = 0; m < 128; ++m) {
    float4 u0 = *(const float4*)&xs4[m * 4];
    float4 u1 = *(const float4*)&xs4[512 + m * 4];
    float4 u2 = *(const float4*)&xs4[1024 + m * 4];
    float4 u3 = *(const float4*)&xs4[1536 + m * 4];
    float4 ov = *(const float4*)&ol[m * 4];
    const float* U0 = (const float*)&u0;
    const float* U1 = (const float*)&u1;
    const float* U2 = (const float*)&u2;
    const float* U3 = (const float*)&u3;
    const float* OV = (const float*)&ov;
#pragma unroll
    for (int j = 0; j < 4; ++j) {
      float cc = cj[j], ss = sj[j];
      re[0] = fmaf(U0[j], cc, re[0]); im[0] = fmaf(-U0[j], ss, im[0]);
      re[1] = fmaf(U1[j], cc, re[1]); im[1] = fmaf(-U1[j], ss, im[1]);
      re[2] = fmaf(U2[j], cc, re[2]); im[2] = fmaf(-U2[j], ss, im[2]);
      re[3] = fmaf(U3[j], cc, re[3]); im[3] = fmaf(-U3[j], ss, im[3]);
      rec   = fmaf(OV[j], cc, rec);   imc   = fmaf(-OV[j], ss, imc);
      float nc = fmaf(cc, c4, -ss * s4);
      sj[j] = fmaf(ss, c4, cc * s4);
      cj[j] = nc;
    }
  }
  const float S = 0.04419417382f;        // 1/sqrt(512)
  const float S1 = S * 0.00390625f;      // S/256
  float* o = fftc + ((bb * NF_ + k) * 16 + fq * 4) * 2;
  float czr = rec * S1, czi = imc * S1;
  o[0] = fmaf(re[0], S, czr); o[1] = fmaf(im[0], S, czi);
  o[2] = fmaf(re[1], S, czr); o[3] = fmaf(im[1], S, czi);
  o[4] = fmaf(re[2], S, czr); o[5] = fmaf(im[2], S, czi);
  o[6] = fmaf(re[3], S, czr); o[7] = fmaf(im[3], S, czi);
  // ---- k = 256: re = sum (-1)^t, im = 0 (both rfft and csd)
  float p0 = xs4[2 * tid] - xs4[2 * tid + 1];
  float p1 = xs4[512 + 2 * tid] - xs4[512 + 2 * tid + 1];
  float p2 = xs4[1024 + 2 * tid] - xs4[1024 + 2 * tid + 1];
  float p3 = xs4[1536 + 2 * tid] - xs4[1536 + 2 * tid + 1];
  float pc = ol[2 * tid] - ol[2 * tid + 1];
#pragma unroll
  for (int off = 32; off; off >>= 1) {
    p0 += __shfl_down(p0, off);
    p1 += __shfl_down(p1, off);
    p2 += __shfl_down(p2, off);
    p3 += __shfl_down(p3, off);
    pc += __shfl_down(pc, off);
  }
  if ((tid & 63) == 0) {
    red2[tid >> 6][0] = p0; red2[tid >> 6][1] = p1;
    red2[tid >> 6][2] = p2; red2[tid >> 6][3] = p3;
    red2[tid >> 6][4] = pc;
  }
  __syncthreads();
  if (tid == 0) {
    float rc = red2[0][4] + red2[1][4] + red2[2][4] + red2[3][4];
#pragma unroll
    for (int f = 0; f < 4; ++f) {
      float rf = red2[0][f] + red2[1][f] + red2[2][f] + red2[3][f];
      float* oo = fftc + ((bb * NF_ + 256) * 16 + fq * 4 + f) * 2;
      oo[0] = fmaf(rf, S, rc * S1);
      oo[1] = 0.f;
    }
  }
}

// ---------- K2: new_fft[b][n][f] from recomputed proj + per-freq complexifier
__global__ __launch_bounds__(256) void k_new(const float* __restrict__ fftc,
                                             const float* __restrict__ W_proj,
                                             const float* __restrict__ b_proj,
                                             const float* __restrict__ mag_w,
                                             const float* __restrict__ mag_b,
                                             const float* __restrict__ phase_w,
                                             const float* __restrict__ phase_b,
                                             float* __restrict__ nf) {
  __shared__ float wp[256], bp[64];
  const int tid = threadIdx.x;
  wp[tid] = W_proj[tid];
  if (tid < 64) bp[tid] = b_proj[tid];
  __syncthreads();
  const int idx = blockIdx.x * 256 + tid;
  const int bn = idx >> 4;
  const int n = bn % NF_;
  float2 z = *(const float2*)(fftc + idx * 2);
  float d = z.x * z.x + z.y * z.y;
  float ir = d > 0.f ? rsqrtf(d) : 0.f;
  float mag = d * ir;
  float sn = z.y * ir;
  float cs = d > 0.f ? z.x * ir : 1.f;
  float fr = (float)n * 0.1953125f;  // 100/512
  float am = 0.f, ap = 0.f;
#pragma unroll 8
  for (int h = 0; h < 64; ++h) {
    float p = fmaf(mag, wp[h], fmaf(sn, wp[64 + h], fmaf(cs, wp[128 + h],
              fmaf(fr, wp[192 + h], bp[h]))));
    p = fmaxf(p, 0.f);
    am = fmaf(p, mag_w[n * 64 + h], am);
    ap = fmaf(p, phase_w[n * 64 + h], ap);
  }
  float m = fmaxf(am + mag_b[n], 0.f);
  float ph = 6.28318530718f / (1.f + __expf(-(ap + phase_b[n])));
  float sp, cp;
  __sincosf(ph, &sp, &cp);
  *(float2*)(nf + idx * 2) = make_float2(m * cp, m * sp);
}

// ---------- K3: gate GEMM. Block: M=128, N=160 (nh), SPK=16 -> 512 blocks.
// Wave tile 64x80 (4m x 5n). XOR-swizzled LDS: col' = kq ^ (row&7) -> both
// staging writes and fragment reads conflict-free. fftc slice cached as bf16.
__global__ __launch_bounds__(256, 2) void k_gemm(const float* __restrict__ fftc,
                                                 const float* __restrict__ W_proj,
                                                 const float* __restrict__ b_proj,
                                                 const unsigned short* __restrict__ wgt,
                                                 unsigned short* __restrict__ gpart) {
  __shared__ __align__(16) unsigned short As[128 * 64];  // 16 KB swizzled
  __shared__ __align__(16) unsigned short Bs[160 * 64];  // 20 KB swizzled
  __shared__ unsigned int zsp[128 * 17];                 // 8.7 KB packed bf16
  const int tid = threadIdx.x;
  const int bid = blockIdx.x;
  const int xcd = bid & 7, jb = bid >> 3;     // jb in [0,64)
  const int mt = jb & 15;
  const int slice = xcd * 4 + (jb >> 4);      // [0,32)
  const int sp = slice >> 1, nh = slice & 1;
  const int i0 = (NF_ * sp) >> 4, i1 = (NF_ * (sp + 1)) >> 4;
  const int ni = i1 - i0;                     // 16 or 17

  // A producer: rows r8+32g (g<4), h-chunk hg*8..+8
  const int r8 = tid >> 3, hg = tid & 7;
  float w0[8], w1[8], w2[8], w3[8], bpv[8];
#pragma unroll
  for (int jj = 0; jj < 8; ++jj) {
    int h = hg * 8 + jj;
    w0[jj] = W_proj[h];       w1[jj] = W_proj[64 + h];
    w2[jj] = W_proj[128 + h]; w3[jj] = W_proj[192 + h];
    bpv[jj] = b_proj[h];
  }
  // B producer: rows nb2+32q (q<5), k-chunk kq*8..+8
  const int nb2 = tid >> 3, kq = tid & 7;
  const unsigned short* bbase = wgt + (nh * 160 + nb2) * KDIM + kq * 8;

  const int lane = tid & 63, wave = tid >> 6;
  const int wm = wave & 1, wn = wave >> 1;
  const int l15 = lane & 15, quad = lane >> 4;

  floatx4 acc[4][5];
#pragma unroll
  for (int a = 0; a < 4; ++a)
#pragma unroll
    for (int b = 0; b < 5; ++b) acc[a][b] = (floatx4){0.f, 0.f, 0.f, 0.f};

  uint4 bv[5];
#pragma unroll
  for (int q = 0; q < 5; ++q)
    bv[q] = *(const uint4*)(bbase + q * (32 * KDIM) + i0 * 64);
  // stage fftc slice (bf16-packed)
  for (int li = tid; li < 128 * ni; li += 256) {
    int r = li & 127, ii = li >> 7;
    int gm = mt * 128 + r;
    float2 z = *(const float2*)(fftc + (((gm >> 4) * NF_ + i0 + ii) * 16 + (gm & 15)) * 2);
    zsp[r * 17 + ii] = f2bf(z.x) | (f2bf(z.y) << 16);
  }
  __syncthreads();

  for (int i = i0; i < i1; ++i) {
    const int ii = i - i0;
    const float fr = (float)i * 0.1953125f;
    unsigned int pk[4][4];
#pragma unroll
    for (int g = 0; g < 4; ++g) {
      unsigned int zp = zsp[(r8 + 32 * g) * 17 + ii];
      float zr = bf2f(zp & 0xFFFFu), zi = bf2f(zp >> 16);
      float d = zr * zr + zi * zi;
      float ir = d > 0.f ? rsqrtf(d) : 0.f;
      float mag = d * ir, sn = zi * ir, cs = d > 0.f ? zr * ir : 1.f;
#pragma unroll
      for (int jj = 0; jj < 4; ++jj) {
        float p0 = fmaf(mag, w0[2 * jj], fmaf(sn, w1[2 * jj],
                   fmaf(cs, w2[2 * jj], fmaf(fr, w3[2 * jj], bpv[2 * jj]))));
        float p1 = fmaf(mag, w0[2 * jj + 1], fmaf(sn, w1[2 * jj + 1],
                   fmaf(cs, w2[2 * jj + 1], fmaf(fr, w3[2 * jj + 1], bpv[2 * jj + 1]))));
        p0 = fmaxf(p0, 0.f); p1 = fmaxf(p1, 0.f);
        pk[g][jj] = f2bf(p0) | (f2bf(p1) << 16);
      }
    }
    __syncthreads();  // prior iteration's fragment reads complete
#pragma unroll
    for (int g = 0; g < 4; ++g) {
      int row = r8 + 32 * g;
      *(uint4*)&As[row * 64 + ((hg ^ (row & 7)) * 8)] =
          make_uint4(pk[g][0], pk[g][1], pk[g][2], pk[g][3]);
    }
#pragma unroll
    for (int q = 0; q < 5; ++q) {
      int row = nb2 + 32 * q;
      *(uint4*)&Bs[row * 64 + ((kq ^ (row & 7)) * 8)] = bv[q];
    }
    __syncthreads();
    {  // prefetch B(i+1): overlaps MFMA phase, consumed next iter pre-barrier
      const int ix = (i + 1 < i1) ? i + 1 : i;
#pragma unroll
      for (int q = 0; q < 5; ++q)
        bv[q] = *(const uint4*)(bbase + q * (32 * KDIM) + ix * 64);
    }
#pragma unroll
    for (int kh = 0; kh < 2; ++kh) {
      const int kqr = kh * 4 + quad;
      short8 af[4];
#pragma unroll
      for (int mi = 0; mi < 4; ++mi) {
        int row = wm * 64 + mi * 16 + l15;
        af[mi] = *(const short8*)&As[row * 64 + ((kqr ^ (row & 7)) * 8)];
      }
#pragma unroll
      for (int nn = 0; nn < 5; ++nn) {
        int row = wn * 80 + nn * 16 + l15;
        short8 bfv = *(const short8*)&Bs[row * 64 + ((kqr ^ (row & 7)) * 8)];
#pragma unroll
        for (int mi = 0; mi < 4; ++mi)
          acc[mi][nn] = __builtin_amdgcn_mfma_f32_16x16x32_bf16(af[mi], bfv,
                                                                acc[mi][nn], 0, 0, 0);
      }
    }
  }
  unsigned short* gp = gpart + (size_t)slice * (2048 * 160);
#pragma unroll
  for (int mi = 0; mi < 4; ++mi)
#pragma unroll
    for (int nn = 0; nn < 5; ++nn)
#pragma unroll
      for (int r = 0; r < 4; ++r) {
        int row = mt * 128 + wm * 64 + mi * 16 + quad * 4 + r;
        int col = wn * 80 + nn * 16 + l15;
        gp[row * 160 + col] = (unsigned short)f2bf(acc[mi][nn][r]);
      }
}

// ---------- K3r: sum split-K bf16 partials + bias -> SiLU -> sigmoid -> w
__global__ __launch_bounds__(256) void k_wred(const unsigned short* __restrict__ gpart,
                                              const float* __restrict__ b_gate,
                                              float* __restrict__ wbuf) {
  const int m = blockIdx.x;
  for (int n = threadIdx.x; n < NF_; n += 256) {
    const int half = (n >= 160) ? 1 : 0;
    const int col = n - half * 160;
    float g = b_gate[n];
#pragma unroll
    for (int s2 = 0; s2 < SPK; ++s2)
      g += bf2f((unsigned int)gpart[((size_t)(s2 * 2 + half) * 2048 + m) * 160 + col]);
    float sg = 1.f / (1.f + __expf(-g));
    float gs = g * sg;
    wbuf[m * NF_ + n] = 1.f / (1.f + __expf(-gs));
  }
}

// ---------- K4: blend + ortho-irfft (chunk-4, 4-phase rotation) + LayerNorm
__global__ __launch_bounds__(256) void k_recon(const float* __restrict__ fftc,
                                               const float* __restrict__ nf,
                                               const float* __restrict__ wbuf,
                                               const float* __restrict__ x,
                                               const float* __restrict__ ln_g,
                                               const float* __restrict__ ln_b,
                                               float* __restrict__ out) {
  __shared__ float wfs[NF_ * 32];  // [k][f][2], Hermitian x2 folded in
  __shared__ float ls1[256], ls2[256];
  const int tid = threadIdx.x, bh = blockIdx.x, bb = blockIdx.y;
  for (int idx = tid; idx < NF_ * 16; idx += 256) {
    int k = idx >> 4, f = idx & 15;
    float2 fz = *(const float2*)(fftc + (bb * (NF_ * 16) + idx) * 2);
    float2 nz = *(const float2*)(nf + (bb * (NF_ * 16) + idx) * 2);
    float wv = wbuf[(bb * 16 + f) * NF_ + k];
    float sc = (k == 0 || k == 256) ? 1.f : 2.f;
    wfs[k * 32 + f * 2] = sc * (fz.x + wv * (nz.x - fz.x));
    wfs[k * 32 + f * 2 + 1] = sc * (fz.y + wv * (nz.y - fz.y));
  }
  __syncthreads();
  const int t = bh * 128 + (tid & 127), fh = tid >> 7;
  const float th = (float)t * 0.01227184630f;
  float c4, s4;
  __sincosf(4.f * th, &s4, &c4);
  float cj[4], sj[4];
  cj[0] = 1.f; sj[0] = 0.f;
  __sincosf(th, &sj[1], &cj[1]);
  __sincosf(2.f * th, &sj[2], &cj[2]);
  __sincosf(3.f * th, &sj[3], &cj[3]);
  float acc[8];
#pragma unroll
  for (int j = 0; j < 8; ++j) acc[j] = 0.f;
  const float4* wp4 = (const float4*)wfs;
  for (int m = 0; m < 64; ++m) {
#pragma unroll
    for (int j = 0; j < 4; ++j) {
      int k = 4 * m + j;
      float4 v0 = wp4[k * 8 + fh * 4 + 0];
      float4 v1 = wp4[k * 8 + fh * 4 + 1];
      float4 v2 = wp4[k * 8 + fh * 4 + 2];
      float4 v3 = wp4[k * 8 + fh * 4 + 3];
      float cc = cj[j], ss = sj[j];
      acc[0] = fmaf(v0.x, cc, acc[0]); acc[0] = fmaf(-v0.y, ss, acc[0]);
      acc[1] = fmaf(v0.z, cc, acc[1]); acc[1] = fmaf(-v0.w, ss, acc[1]);
      acc[2] = fmaf(v1.x, cc, acc[2]); acc[2] = fmaf(-v1.y, ss, acc[2]);
      acc[3] = fmaf(v1.z, cc, acc[3]); acc[3] = fmaf(-v1.w, ss, acc[3]);
      acc[4] = fmaf(v2.x, cc, acc[4]); acc[4] = fmaf(-v2.y, ss, acc[4]);
      acc[5] = fmaf(v2.z, cc, acc[5]); acc[5] = fmaf(-v2.w, ss, acc[5]);
      acc[6] = fmaf(v3.x, cc, acc[6]); acc[6] = fmaf(-v3.y, ss, acc[6]);
      acc[7] = fmaf(v3.z, cc, acc[7]); acc[7] = fmaf(-v3.w, ss, acc[7]);
      float nc = fmaf(cc, c4, -ss * s4);
      sj[j] = fmaf(ss, c4, cc * s4);
      cj[j] = nc;
    }
  }
  {  // k = 256: cos(pi*t) = (-1)^t, sin = 0
    float sg = (t & 1) ? -1.f : 1.f;
    float4 v0 = wp4[256 * 8 + fh * 4 + 0];
    float4 v1 = wp4[256 * 8 + fh * 4 + 1];
    float4 v2 = wp4[256 * 8 + fh * 4 + 2];
    float4 v3 = wp4[256 * 8 + fh * 4 + 3];
    acc[0] = fmaf(v0.x, sg, acc[0]); acc[1] = fmaf(v0.z, sg, acc[1]);
    acc[2] = fmaf(v1.x, sg, acc[2]); acc[3] = fmaf(v1.z, sg, acc[3]);
    acc[4] = fmaf(v2.x, sg, acc[4]); acc[5] = fmaf(v2.z, sg, acc[5]);
    acc[6] = fmaf(v3.x, sg, acc[6]); acc[7] = fmaf(v3.z, sg, acc[7]);
  }
  const float S = 0.04419417382f;
  const float* xr = x + (bb * 512 + t) * 16 + fh * 8;
  float4 xa = *(const float4*)xr, xb = *(const float4*)(xr + 4);
  float y[8];
  y[0] = fmaf(acc[0], S, xa.x); y[1] = fmaf(acc[1], S, xa.y);
  y[2] = fmaf(acc[2], S, xa.z); y[3] = fmaf(acc[3], S, xa.w);
  y[4] = fmaf(acc[4], S, xb.x); y[5] = fmaf(acc[5], S, xb.y);
  y[6] = fmaf(acc[6], S, xb.z); y[7] = fmaf(acc[7], S, xb.w);
  float s1 = 0.f, s2 = 0.f;
#pragma unroll
  for (int j = 0; j < 8; ++j) { s1 += y[j]; s2 = fmaf(y[j], y[j], s2); }
  ls1[tid] = s1; ls2[tid] = s2;
  __syncthreads();
  const int o = tid ^ 128;
  float t1 = s1 + ls1[o], t2 = s2 + ls2[o];
  float mu = t1 * 0.0625f;
  float var = t2 * 0.0625f - mu * mu;
  float rs = rsqrtf(var + 1e-5f);
  float* orow = out + (bb * 512 + t) * 16 + fh * 8;
  float4 o0, o1;
  o0.x = (y[0] - mu) * rs * ln_g[fh * 8 + 0] + ln_b[fh * 8 + 0];
  o0.y = (y[1] - mu) * rs * ln_g[fh * 8 + 1] + ln_b[fh * 8 + 1];
  o0.z = (y[2] - mu) * rs * ln_g[fh * 8 + 2] + ln_b[fh * 8 + 2];
  o0.w = (y[3] - mu) * rs * ln_g[fh * 8 + 3] + ln_b[fh * 8 + 3];
  o1.x = (y[4] - mu) * rs * ln_g[fh * 8 + 4] + ln_b[fh * 8 + 4];
  o1.y = (y[5] - mu) * rs * ln_g[fh * 8 + 5] + ln_b[fh * 8 + 5];
  o1.z = (y[6] - mu) * rs * ln_g[fh * 8 + 6] + ln_b[fh * 8 + 6];
  o1.w = (y[7] - mu) * rs * ln_g[fh * 8 + 7] + ln_b[fh * 8 + 7];
  *(float4*)orow = o0;
  *(float4*)(orow + 4) = o1;
}

extern "C" void kernel_launch(void* const* d_in, const int* in_sizes, int n_in,
                              void* d_out, int out_size, void* d_ws, size_t ws_size,
                              hipStream_t stream) {
  const float* x = (const float*)d_in[0];
  const float* W_proj = (const float*)d_in[1];
  const float* b_proj = (const float*)d_in[2];
  const float* W_gate = (const float*)d_in[3];
  const float* b_gate = (const float*)d_in[4];
  const float* mag_w = (const float*)d_in[5];
  const float* mag_b = (const float*)d_in[6];
  const float* phase_w = (const float*)d_in[7];
  const float* phase_b = (const float*)d_in[8];
  const float* ln_g = (const float*)d_in[9];
  const float* ln_b = (const float*)d_in[10];
  float* out = (float*)d_out;
  float* ws = (float*)d_ws;

  // workspace (float slots), ~42 MB total (d_ws is 256 MB)
  float* fftc = ws;                                        // 1,052,672
  float* nfb = ws + 1052672;                               // 1,052,672
  float* wbuf = ws + 2105344;                              //   526,336
  unsigned short* gpart = (unsigned short*)(ws + 2631680); // 32*2048*160 bf16
  unsigned short* wgt = (unsigned short*)(ws + 7874560);   // 320*16448 bf16

  hipLaunchKernelGGL(k_wgt, dim3(257, 10), dim3(256), 0, stream, W_gate, wgt);
  hipLaunchKernelGGL(k_fft, dim3(4, 128), dim3(256), 0, stream, x, fftc);
  hipLaunchKernelGGL(k_new, dim3(2056), dim3(256), 0, stream, fftc, W_proj, b_proj,
                     mag_w, mag_b, phase_w, phase_b, nfb);
  hipLaunchKernelGGL(k_gemm, dim3(512), dim3(256), 0, stream, fftc, W_proj,
                     b_proj, wgt, gpart);
  hipLaunchKernelGGL(k_wred, dim3(2048), dim3(256), 0, stream, gpart, b_gate, wbuf);
  hipLaunchKernelGGL(k_recon, dim3(4, 128), dim3(256), 0, stream, fftc, nfb, wbuf, x,
                     ln_g, ln_b, out);
}